// Round 4
// baseline (777.905 us; speedup 1.0000x reference)
//
#include <hip/hip_runtime.h>

using u16 = unsigned short;
using u32 = unsigned int;

typedef __attribute__((ext_vector_type(4))) float f32x4;
typedef __attribute__((ext_vector_type(8))) short frag8;   // 8 x bf16 (4 VGPRs)

#define HIDDEN 2048
#define SEQ    2048
#define NHEADS 16
#define HDIM   128

__device__ __forceinline__ float bf2f(u16 u) {
  union { u32 i; float f; } c; c.i = ((u32)u) << 16; return c.f;
}
// RNE f32 -> bf16 (inputs are clean f32; no NaN guard needed)
__device__ __forceinline__ u16 f2bf_rne(float f) {
  union { float f; u32 i; } c; c.f = f;
  u32 u = c.i + 0x7fffu + ((c.i >> 16) & 1u);
  return (u16)(u >> 16);
}
// sanitizing f32 -> bf16 (inf/NaN -> 0) for internal stores (defensive round)
__device__ __forceinline__ u16 f2bf(float f) {
  union { float f; u32 i; } c; c.f = f;
  if ((c.i & 0x7f800000u) == 0x7f800000u) return 0;
  u32 u = c.i + 0x7fffu + ((c.i >> 16) & 1u);
  return (u16)(u >> 16);
}

// ---------------------------------------------------------------------------
// NT GEMM:  C[m,n] = sum_k A[m,k] * W[n,k] + bias[n]
// A: [4096 x 2048] row-major (f32 if A_F32 else bf16)
// W: [2048 x 2048] row-major f32;  bias f32
// C: row-major [4096][2048] (f32 if C_F32 else bf16)
// Compute path: convert to bf16 during LDS staging, 16x16x32 bf16 MFMA,
// fp32 accum.  128x128 tile, BK=32, plain vectorized staging.
// ---------------------------------------------------------------------------
template<int A_F32, int C_F32>
__global__ __launch_bounds__(256, 2)
void gemm_bias(const void* __restrict__ Av, const float* __restrict__ W,
               const float* __restrict__ bias, void* __restrict__ Cv)
{
  __shared__ __align__(16) u16 As[4096];   // 128 rows x 32 k (bf16)
  __shared__ __align__(16) u16 Bs[4096];

  const int tid  = threadIdx.x;
  const int lane = tid & 63;
  const int wv   = tid >> 6;
  const int quad = lane >> 4;
  const int l16  = lane & 15;
  const int wm = wv >> 1, wn = wv & 1;
  const int m0 = blockIdx.y * 128;
  const int n0 = blockIdx.x * 128;

  f32x4 acc[4][4];
#pragma unroll
  for (int i = 0; i < 4; i++)
#pragma unroll
    for (int j = 0; j < 4; j++) acc[i][j] = (f32x4)0.0f;

  // granule g in [0,512): 8 elements each; g -> tile row g>>2, k-col (g&3)*8
  const int g0 = tid, g1 = tid + 256;
  const int r0 = g0 >> 2, c0 = (g0 & 3) * 8;
  const int r1 = g1 >> 2, c1 = (g1 & 3) * 8;

  const float* Af = (const float*)Av;
  const u16*   Ab = (const u16*)Av;

  for (int k0 = 0; k0 < HIDDEN; k0 += 32) {
    // ---- A granules (convert f32->bf16 if needed)
    frag8 a0, a1;
    if (A_F32) {
      const float* p0 = Af + (size_t)(m0 + r0) * HIDDEN + k0 + c0;
      const float* p1 = Af + (size_t)(m0 + r1) * HIDDEN + k0 + c1;
      f32x4 x0 = *(const f32x4*)p0, x1 = *(const f32x4*)(p0 + 4);
      f32x4 y0 = *(const f32x4*)p1, y1 = *(const f32x4*)(p1 + 4);
#pragma unroll
      for (int e = 0; e < 4; e++) {
        a0[e]   = (short)f2bf_rne(x0[e]);
        a0[e+4] = (short)f2bf_rne(x1[e]);
        a1[e]   = (short)f2bf_rne(y0[e]);
        a1[e+4] = (short)f2bf_rne(y1[e]);
      }
    } else {
      a0 = *(const frag8*)(Ab + (size_t)(m0 + r0) * HIDDEN + k0 + c0);
      a1 = *(const frag8*)(Ab + (size_t)(m0 + r1) * HIDDEN + k0 + c1);
    }
    // ---- W granules (always f32 -> bf16)
    frag8 b0, b1;
    {
      const float* p0 = W + (size_t)(n0 + r0) * HIDDEN + k0 + c0;
      const float* p1 = W + (size_t)(n0 + r1) * HIDDEN + k0 + c1;
      f32x4 x0 = *(const f32x4*)p0, x1 = *(const f32x4*)(p0 + 4);
      f32x4 y0 = *(const f32x4*)p1, y1 = *(const f32x4*)(p1 + 4);
#pragma unroll
      for (int e = 0; e < 4; e++) {
        b0[e]   = (short)f2bf_rne(x0[e]);
        b0[e+4] = (short)f2bf_rne(x1[e]);
        b1[e]   = (short)f2bf_rne(y0[e]);
        b1[e+4] = (short)f2bf_rne(y1[e]);
      }
    }
    *(frag8*)&As[g0 * 8] = a0;
    *(frag8*)&As[g1 * 8] = a1;
    *(frag8*)&Bs[g0 * 8] = b0;
    *(frag8*)&Bs[g1 * 8] = b1;
    __syncthreads();

    frag8 af[4], bfr[4];
#pragma unroll
    for (int mt = 0; mt < 4; mt++)
      af[mt] = *(const frag8*)&As[(wm*64 + mt*16 + l16) * 32 + quad*8];
#pragma unroll
    for (int nt = 0; nt < 4; nt++)
      bfr[nt] = *(const frag8*)&Bs[(wn*64 + nt*16 + l16) * 32 + quad*8];
#pragma unroll
    for (int mt = 0; mt < 4; mt++)
#pragma unroll
      for (int nt = 0; nt < 4; nt++)
        acc[mt][nt] = __builtin_amdgcn_mfma_f32_16x16x32_bf16(af[mt], bfr[nt], acc[mt][nt], 0, 0, 0);

    __syncthreads();
  }

  // C/D layout (m89/m91): col(n) = lane&15, row(m) = (lane>>4)*4 + reg
#pragma unroll
  for (int nt = 0; nt < 4; nt++) {
    const int n  = n0 + wn*64 + nt*16 + l16;
    const float bv = bias[n];
#pragma unroll
    for (int mt = 0; mt < 4; mt++) {
#pragma unroll
      for (int r = 0; r < 4; r++) {
        const int m = m0 + wm*64 + mt*16 + quad*4 + r;
        if (C_F32) ((float*)Cv)[(size_t)m * HIDDEN + n] = acc[mt][nt][r] + bv;
        else       ((u16*)Cv)[(size_t)m * HIDDEN + n]   = f2bf(acc[mt][nt][r] + bv);
      }
    }
  }
}

// ---------------------------------------------------------------------------
// RoPE in place on bf16 Q and K ([4096][2048], col = h*128 + d, s = row%2048)
// pair (d, d+64), d in [0,64)
// ---------------------------------------------------------------------------
__global__ void rope_kernel(u16* __restrict__ Q, u16* __restrict__ K)
{
  const int tid = blockIdx.x * 256 + threadIdx.x;
  if (tid >= 2 * 4096 * 1024) return;
  const int t   = tid >> 22;          // 0:Q 1:K
  const int r   = tid & 4194303;
  const int row = r >> 10;
  const int p   = r & 1023;
  const int h   = p >> 6, d = p & 63;
  u16* X = t ? K : Q;
  const int s = row & 2047;
  const float inv = __expf(-(float)d * (9.210340371976184f / 64.0f));  // 10000^(-d/64)
  const float ang = (float)s * inv;
  const float c = cosf(ang), sn = sinf(ang);
  const size_t base = (size_t)row * HIDDEN + h * HDIM + d;
  const float x1 = bf2f(X[base]);
  const float x2 = bf2f(X[base + 64]);
  X[base]      = f2bf(x1 * c - x2 * sn);
  X[base + 64] = f2bf(x2 * c + x1 * sn);
}

// ---------------------------------------------------------------------------
// Flash attention (causal), defensive formulation (unchanged from round 3).
// Q,K,V: bf16 [4096][2048] (Q,K rope'd).  O: merged bf16 [4096][2048]
// (aliases Q; each block writes exactly the region only it reads).
// Block: 256 thr = 4 waves; Q-tile 128 (32 q/wave), K-tile 64.
// ---------------------------------------------------------------------------
__global__ __launch_bounds__(256, 2)
void attn_kernel(const u16* Q, const u16* __restrict__ K,
                 const u16* __restrict__ V, u16* O)
{
  __shared__ __align__(16) u16 Ks[64 * 136];    // [key][d], stride 136
  __shared__ __align__(16) u16 Vs[128 * 72];    // [d][j],   stride 72
  __shared__ __align__(16) u16 Ps[4 * 32 * 72]; // per-wave [query][j], stride 72

  const int bx = blockIdx.x;
  const int g  = bx >> 5;
  const int bh = bx & 31;
  const int qt = (g & 1) ? (15 - (g >> 1)) : (g >> 1);   // zigzag load balance
  const int b = bh >> 4, h = bh & 15;

  const int tid = threadIdx.x, lane = tid & 63, wv = tid >> 6;
  const int quad = lane >> 4, l16 = lane & 15;

  // Q A-fragments: lane holds Q[m = mt*16+l16][d = ks*32 + quad*8 + j]
  frag8 qf[2][4];
  const size_t qbase = ((size_t)(b * SEQ) + qt*128 + wv*32) * HIDDEN + h * HDIM;
#pragma unroll
  for (int mt = 0; mt < 2; mt++)
#pragma unroll
    for (int ks = 0; ks < 4; ks++)
      qf[mt][ks] = *(const frag8*)(Q + qbase + (size_t)(mt*16 + l16) * HIDDEN + ks*32 + quad*8);

  f32x4 Oacc[2][8];
#pragma unroll
  for (int mt = 0; mt < 2; mt++)
#pragma unroll
    for (int dt = 0; dt < 8; dt++) Oacc[mt][dt] = (f32x4)0.0f;
  float m_i[2][4], l_i[2][4];
#pragma unroll
  for (int mt = 0; mt < 2; mt++)
#pragma unroll
    for (int r = 0; r < 4; r++) { m_i[mt][r] = -1e30f; l_i[mt][r] = 0.0f; }

  const int ktmax = 2 * qt + 2;
  const size_t row0 = (size_t)(b * SEQ) * HIDDEN + h * HDIM;
  u16* Pw = Ps + wv * (32 * 72);

  for (int kt = 0; kt < ktmax; kt++) {
    // ---- stage K tile [64 keys][128 d] -> Ks[key*136 + d] (16B vector)
#pragma unroll
    for (int it = 0; it < 4; it++) {
      const int G = it * 256 + tid;          // 0..1023
      const int key = G >> 4, gd = (G & 15) * 8;
      *(frag8*)&Ks[key * 136 + gd] =
        *(const frag8*)(K + row0 + (size_t)(kt*64 + key) * HIDDEN + gd);
    }
    // ---- stage V tile transposed: Vs[d*72 + j]
#pragma unroll
    for (int it = 0; it < 4; it++) {
      const int G = it * 256 + tid;
      const int jg = G & 63, dg = G >> 6;
      frag8 v = *(const frag8*)(V + row0 + (size_t)(kt*64 + jg) * HIDDEN + dg*8);
#pragma unroll
      for (int e = 0; e < 8; e++)
        Vs[(dg*8 + e) * 72 + jg] = (u16)v[e];
    }
    __syncthreads();

    // ---- S = Q*K^T : per wave 32 queries x 64 keys
    f32x4 st[2][4];
#pragma unroll
    for (int mt = 0; mt < 2; mt++)
#pragma unroll
      for (int jt = 0; jt < 4; jt++) st[mt][jt] = (f32x4)0.0f;

#pragma unroll
    for (int ks = 0; ks < 4; ks++) {
      frag8 kf[4];
#pragma unroll
      for (int jt = 0; jt < 4; jt++)
        kf[jt] = *(const frag8*)&Ks[(jt*16 + l16) * 136 + ks*32 + quad*8];
#pragma unroll
      for (int mt = 0; mt < 2; mt++)
#pragma unroll
        for (int jt = 0; jt < 4; jt++)
          st[mt][jt] = __builtin_amdgcn_mfma_f32_16x16x32_bf16(qf[mt][ks], kf[jt], st[mt][jt], 0, 0, 0);
    }

    // ---- scale, clamp, causal mask.  row(query) = quad*4+r, col(key) = l16
    const float scale = 0.08838834764831845f;   // 1/sqrt(128)
#pragma unroll
    for (int mt = 0; mt < 2; mt++)
#pragma unroll
      for (int jt = 0; jt < 4; jt++) {
        const int j = kt*64 + jt*16 + l16;
#pragma unroll
        for (int r = 0; r < 4; r++) {
          const int m = qt*128 + wv*32 + mt*16 + quad*4 + r;
          float v = st[mt][jt][r] * scale;
          v = fminf(fmaxf(v, -30.0f), 30.0f);   // exp can never overflow
          st[mt][jt][r] = (j <= m) ? v : -1e30f;
        }
      }

    // ---- online softmax per query row (mt, r); reduce over l16 lanes
    float alpha[2][4];
#pragma unroll
    for (int mt = 0; mt < 2; mt++)
#pragma unroll
      for (int r = 0; r < 4; r++) {
        float cm = st[mt][0][r];
#pragma unroll
        for (int jt = 1; jt < 4; jt++) cm = fmaxf(cm, st[mt][jt][r]);
        cm = fmaxf(cm, __shfl_xor(cm, 1, 64));
        cm = fmaxf(cm, __shfl_xor(cm, 2, 64));
        cm = fmaxf(cm, __shfl_xor(cm, 4, 64));
        cm = fmaxf(cm, __shfl_xor(cm, 8, 64));
        const float mnew = fmaxf(m_i[mt][r], cm);
        alpha[mt][r] = __expf(fminf(m_i[mt][r] - mnew, 0.0f));
        m_i[mt][r] = mnew;
      }

    // ---- p = exp(s - m) (masked -> 0); P -> LDS (sanitized bf16)
    float csum[2][4];
#pragma unroll
    for (int mt = 0; mt < 2; mt++)
#pragma unroll
      for (int r = 0; r < 4; r++) csum[mt][r] = 0.0f;
#pragma unroll
    for (int mt = 0; mt < 2; mt++)
#pragma unroll
      for (int jt = 0; jt < 4; jt++)
#pragma unroll
        for (int r = 0; r < 4; r++) {
          const float sv = st[mt][jt][r];
          const float p = (sv > -0.5e30f) ? __expf(fminf(sv - m_i[mt][r], 0.0f)) : 0.0f;
          csum[mt][r] += p;
          Pw[(mt*16 + quad*4 + r) * 72 + jt*16 + l16] = f2bf(p);
        }
#pragma unroll
    for (int mt = 0; mt < 2; mt++)
#pragma unroll
      for (int r = 0; r < 4; r++) {
        float cs = csum[mt][r];
        cs += __shfl_xor(cs, 1, 64);
        cs += __shfl_xor(cs, 2, 64);
        cs += __shfl_xor(cs, 4, 64);
        cs += __shfl_xor(cs, 8, 64);
        l_i[mt][r] = l_i[mt][r] * alpha[mt][r] + cs;
#pragma unroll
        for (int dt = 0; dt < 8; dt++) Oacc[mt][dt][r] *= alpha[mt][r];
      }

    __syncthreads();   // bulletproof: P visible to all (same-wave in theory)

    // ---- O += P * V.  A-frag = P[m=l16][j=quad*8+jj]; B-frag = V[n=d][k=j]
#pragma unroll
    for (int ks2 = 0; ks2 < 2; ks2++) {
      frag8 pf[2];
#pragma unroll
      for (int mt = 0; mt < 2; mt++)
        pf[mt] = *(const frag8*)&Pw[(mt*16 + l16) * 72 + ks2*32 + quad*8];
#pragma unroll
      for (int dt = 0; dt < 8; dt++) {
        frag8 vf = *(const frag8*)&Vs[(dt*16 + l16) * 72 + ks2*32 + quad*8];
#pragma unroll
        for (int mt = 0; mt < 2; mt++)
          Oacc[mt][dt] = __builtin_amdgcn_mfma_f32_16x16x32_bf16(pf[mt], vf, Oacc[mt][dt], 0, 0, 0);
      }
    }
    __syncthreads();
  }

  // ---- finalize: /l_i (guarded), store merged [b*2048+m][h*128+d]
#pragma unroll
  for (int mt = 0; mt < 2; mt++)
#pragma unroll
    for (int r = 0; r < 4; r++) {
      const float inv = 1.0f / fmaxf(l_i[mt][r], 1e-20f);
      const int m = qt*128 + wv*32 + mt*16 + quad*4 + r;
#pragma unroll
      for (int dt = 0; dt < 8; dt++) {
        const int d = dt*16 + l16;
        O[((size_t)(b * SEQ) + m) * HIDDEN + h * HDIM + d] = f2bf(Oacc[mt][dt][r] * inv);
      }
    }
}

// ---------------------------------------------------------------------------
extern "C" void kernel_launch(void* const* d_in, const int* in_sizes, int n_in,
                              void* d_out, int out_size, void* d_ws, size_t ws_size,
                              hipStream_t stream)
{
  // Reference dtypes are float32 -> all inputs f32, output f32.
  const float* X  = (const float*)d_in[0];
  const float* Wq = (const float*)d_in[1];
  const float* bq = (const float*)d_in[2];
  const float* Wk = (const float*)d_in[3];
  const float* bk = (const float*)d_in[4];
  const float* Wv = (const float*)d_in[5];
  const float* bv = (const float*)d_in[6];
  const float* Wo = (const float*)d_in[7];
  const float* bo = (const float*)d_in[8];
  float* out = (float*)d_out;

  // bf16 intermediates. ws usage: 32 MB. K scratch lives in d_out (f32 out is
  // 33.5 MB; K dead before final GEMM writes it).
  char* ws = (char*)d_ws;
  u16* Qb = (u16*)ws;                          // 16 MB; attn output aliases this
  u16* Vb = (u16*)(ws + (size_t)(16 << 20));   // 16 MB
  u16* Kb = (u16*)d_out;                       // 16 MB scratch

  dim3 gg(16, 32), blk(256);
  gemm_bias<1,0><<<gg, blk, 0, stream>>>(X, Wq, bq, Qb);
  gemm_bias<1,0><<<gg, blk, 0, stream>>>(X, Wk, bk, Kb);
  gemm_bias<1,0><<<gg, blk, 0, stream>>>(X, Wv, bv, Vb);
  rope_kernel<<<32768, 256, 0, stream>>>(Qb, Kb);
  attn_kernel<<<512, blk, 0, stream>>>(Qb, Kb, Vb, Qb);   // ctx -> Qb
  gemm_bias<0,1><<<gg, blk, 0, stream>>>(Qb, Wo, bo, out);
}

// Round 5
// 584.888 us; speedup vs baseline: 1.3300x; 1.3300x over previous
//
#include <hip/hip_runtime.h>

using u16 = unsigned short;
using u32 = unsigned int;

typedef __attribute__((ext_vector_type(4))) float f32x4;
typedef __attribute__((ext_vector_type(8))) short frag8;   // 8 x bf16 (4 VGPRs)

#define HIDDEN 2048
#define SEQ    2048
#define NHEADS 16
#define HDIM   128

__device__ __forceinline__ float bf2f(u16 u) {
  union { u32 i; float f; } c; c.i = ((u32)u) << 16; return c.f;
}
__device__ __forceinline__ u16 f2bf(float f) {   // RNE
  union { float f; u32 i; } c; c.f = f;
  u32 u = c.i + 0x7fffu + ((c.i >> 16) & 1u);
  return (u16)(u >> 16);
}

// ---------------------------------------------------------------------------
// f32 -> bf16 bulk convert (8 elems/thread, 16B stores)
// ---------------------------------------------------------------------------
__global__ void cvt_kernel(const float* __restrict__ src, u16* __restrict__ dst, int n8)
{
  const int t = blockIdx.x * 256 + threadIdx.x;
  if (t >= n8) return;
  const float* p = src + (size_t)t * 8;
  f32x4 x0 = *(const f32x4*)p, x1 = *(const f32x4*)(p + 4);
  frag8 o;
#pragma unroll
  for (int e = 0; e < 4; e++) { o[e] = (short)f2bf(x0[e]); o[e+4] = (short)f2bf(x1[e]); }
  *(frag8*)(dst + (size_t)t * 8) = o;
}

// ---------------------------------------------------------------------------
// Fused NT GEMM:  C[m,n] = sum_k A[m,k] * W[n,k] + bias[n]
// A: bf16 [4096 x 2048] (staged via global_load_lds width=16, m97 structure)
// W: bf16 (W_BF16=1, DMA) or f32 (W_BF16=0, VGPR-convert staging)
// NW: number of fused weights (grid.x = NW*16); VT: wix==2 stores transposed
//     Vt[(b*2048 + n)*2048 + s];  C_F32: store f32 (out-proj) else bf16.
// 128x128 tile, BK=32, 16x16x32 bf16 MFMA, fp32 accum.
// ---------------------------------------------------------------------------
template<int W_BF16, int NW, int VT, int C_F32>
__global__ __launch_bounds__(256, 4)
void gemm_fused(const u16* __restrict__ A,
                const void* __restrict__ W0, const void* __restrict__ W1,
                const void* __restrict__ W2,
                const float* __restrict__ bias0, const float* __restrict__ bias1,
                const float* __restrict__ bias2,
                void* __restrict__ C0, void* __restrict__ C1, void* __restrict__ C2)
{
  __shared__ __align__(16) u16 smem[8192];     // As [0,4096), Bs [4096,8192)
  u16* As = smem;
  u16* Bs = smem + 4096;

  const int tid  = threadIdx.x;
  const int lane = tid & 63;
  const int wv   = tid >> 6;
  const int quad = lane >> 4;
  const int l16  = lane & 15;
  const int wm = wv >> 1, wn = wv & 1;
  const int m0 = blockIdx.y * 128;
  const int wix = (NW == 1) ? 0 : (blockIdx.x >> 4);
  const int n0  = ((NW == 1) ? blockIdx.x : (blockIdx.x & 15)) * 128;

  const void* Wp = (wix == 0) ? W0 : (wix == 1) ? W1 : W2;
  const float* bias = (wix == 0) ? bias0 : (wix == 1) ? bias1 : bias2;
  void* Cp = (wix == 0) ? C0 : (wix == 1) ? C1 : C2;

  f32x4 acc[4][4];
#pragma unroll
  for (int i = 0; i < 4; i++)
#pragma unroll
    for (int j = 0; j < 4; j++) acc[i][j] = (f32x4)0.0f;

  // granule g in [0,512): 16B; g -> tile row g>>2, k-col (g&3)*8
  const int g0 = tid, g1 = tid + 256;
  const int r0 = g0 >> 2, c0 = (g0 & 3) * 8;
  const int r1 = g1 >> 2, c1 = (g1 & 3) * 8;

  for (int k0 = 0; k0 < HIDDEN; k0 += 32) {
    // ---- A: async DMA (LDS dest = wave-uniform base + lane*16)
    __builtin_amdgcn_global_load_lds(
      (const __attribute__((address_space(1))) void*)(A + (size_t)(m0 + r0) * HIDDEN + k0 + c0),
      (__attribute__((address_space(3))) void*)(As + g0 * 8), 16, 0, 0);
    __builtin_amdgcn_global_load_lds(
      (const __attribute__((address_space(1))) void*)(A + (size_t)(m0 + r1) * HIDDEN + k0 + c1),
      (__attribute__((address_space(3))) void*)(As + g1 * 8), 16, 0, 0);
    // ---- W: DMA (bf16) or convert-staging (f32)
    if (W_BF16) {
      const u16* Wb = (const u16*)Wp;
      __builtin_amdgcn_global_load_lds(
        (const __attribute__((address_space(1))) void*)(Wb + (size_t)(n0 + r0) * HIDDEN + k0 + c0),
        (__attribute__((address_space(3))) void*)(Bs + g0 * 8), 16, 0, 0);
      __builtin_amdgcn_global_load_lds(
        (const __attribute__((address_space(1))) void*)(Wb + (size_t)(n0 + r1) * HIDDEN + k0 + c1),
        (__attribute__((address_space(3))) void*)(Bs + g1 * 8), 16, 0, 0);
    } else {
      const float* Wf = (const float*)Wp;
      const float* p0 = Wf + (size_t)(n0 + r0) * HIDDEN + k0 + c0;
      const float* p1 = Wf + (size_t)(n0 + r1) * HIDDEN + k0 + c1;
      f32x4 x0 = *(const f32x4*)p0, x1 = *(const f32x4*)(p0 + 4);
      f32x4 y0 = *(const f32x4*)p1, y1 = *(const f32x4*)(p1 + 4);
      frag8 b0v, b1v;
#pragma unroll
      for (int e = 0; e < 4; e++) {
        b0v[e]   = (short)f2bf(x0[e]); b0v[e+4] = (short)f2bf(x1[e]);
        b1v[e]   = (short)f2bf(y0[e]); b1v[e+4] = (short)f2bf(y1[e]);
      }
      *(frag8*)&Bs[g0 * 8] = b0v;
      *(frag8*)&Bs[g1 * 8] = b1v;
    }

    __builtin_amdgcn_s_waitcnt(0);   // drain DMA before barrier
    __syncthreads();

    frag8 af[4], bfr[4];
#pragma unroll
    for (int mt = 0; mt < 4; mt++)
      af[mt] = *(const frag8*)&As[(wm*64 + mt*16 + l16) * 32 + quad*8];
#pragma unroll
    for (int nt = 0; nt < 4; nt++)
      bfr[nt] = *(const frag8*)&Bs[(wn*64 + nt*16 + l16) * 32 + quad*8];
#pragma unroll
    for (int mt = 0; mt < 4; mt++)
#pragma unroll
      for (int nt = 0; nt < 4; nt++)
        acc[mt][nt] = __builtin_amdgcn_mfma_f32_16x16x32_bf16(af[mt], bfr[nt], acc[mt][nt], 0, 0, 0);

    __syncthreads();
  }

  // C/D layout (m89/m91): col(n) = lane&15, row(m) = (lane>>4)*4 + reg
  if (VT && wix == 2) {
    // transposed store: Vt[(b*2048 + n)*2048 + s],  b = m>>11, s = m&2047
    u16* Cv = (u16*)Cp;
    u16* T = smem + wv * 1056;    // per-wave 16 x 66 (smem reuse, post-barrier)
#pragma unroll
    for (int nt = 0; nt < 4; nt++) {
      const int n  = n0 + wn*64 + nt*16 + l16;
      const float bv = bias[n];
#pragma unroll
      for (int mt = 0; mt < 4; mt++)
#pragma unroll
        for (int r = 0; r < 4; r++)
          T[l16 * 66 + mt*16 + quad*4 + r] = f2bf(acc[mt][nt][r] + bv);
      // same-wave LDS RAW (compiler inserts lgkmcnt wait)
#pragma unroll
      for (int rr = 0; rr < 16; rr++) {
        const int nn = n0 + wn*64 + nt*16 + rr;
        const int mm = m0 + wm*64 + lane;
        const int b = mm >> 11, s = mm & 2047;
        Cv[((size_t)(b * HIDDEN + nn)) * SEQ + s] = T[rr * 66 + lane];
      }
    }
  } else {
#pragma unroll
    for (int nt = 0; nt < 4; nt++) {
      const int n  = n0 + wn*64 + nt*16 + l16;
      const float bv = bias[n];
#pragma unroll
      for (int mt = 0; mt < 4; mt++) {
#pragma unroll
        for (int r = 0; r < 4; r++) {
          const int m = m0 + wm*64 + mt*16 + quad*4 + r;
          if (C_F32) ((float*)Cp)[(size_t)m * HIDDEN + n] = acc[mt][nt][r] + bv;
          else       ((u16*)Cp)[(size_t)m * HIDDEN + n]   = f2bf(acc[mt][nt][r] + bv);
        }
      }
    }
  }
}

// ---------------------------------------------------------------------------
// RoPE in place on bf16 Q,K; vectorized 8 d/thread.  Q additionally
// pre-scaled by 1/sqrt(128) (moves the score scaling out of attention).
// ---------------------------------------------------------------------------
__global__ void rope_kernel(u16* __restrict__ Q, u16* __restrict__ K)
{
  const int tid = blockIdx.x * 256 + threadIdx.x;   // 2^20 total
  const int t   = tid >> 19;           // 0:Q 1:K
  const int r   = tid & 524287;
  const int row = r >> 7;              // [0,4096)
  const int grp = r & 127;
  const int h   = grp >> 3, d0 = (grp & 7) * 8;
  u16* X = t ? K : Q;
  const float s = (float)(row & 2047);
  const float qscale = t ? 1.0f : 0.08838834764831845f;
  const size_t base = (size_t)row * HIDDEN + h * HDIM + d0;
  frag8 a = *(const frag8*)(X + base);
  frag8 b = *(const frag8*)(X + base + 64);
  frag8 oa, ob;
#pragma unroll
  for (int e = 0; e < 8; e++) {
    const float inv = __expf(-(float)(d0 + e) * (9.210340371976184f / 64.0f));
    float sn, c;
    __sincosf(s * inv, &sn, &c);
    const float x1 = bf2f((u16)a[e]), x2 = bf2f((u16)b[e]);
    oa[e] = (short)f2bf((x1 * c - x2 * sn) * qscale);
    ob[e] = (short)f2bf((x2 * c + x1 * sn) * qscale);
  }
  *(frag8*)(X + base)      = oa;
  *(frag8*)(X + base + 64) = ob;
}

// ---------------------------------------------------------------------------
// Flash attention (causal).  Q (pre-scaled), K: bf16 [4096][2048];
// Vt: bf16 [(b*2048 + h*128 + d)][s].  O: merged bf16 [4096][2048] (aliases Q).
// Block: 256 thr = 4 waves; Q-tile 128 (32 q/wave), K-tile 64.
// ---------------------------------------------------------------------------
#define KS_STR 132
#define VS_STR 68
#define PS_STR 68
__global__ __launch_bounds__(256, 3)
void attn_kernel(const u16* Q, const u16* __restrict__ K,
                 const u16* __restrict__ Vt, u16* O)
{
  __shared__ __align__(16) u16 Ks[64 * KS_STR];    // [key][d]
  __shared__ __align__(16) u16 Vs[128 * VS_STR];   // [d][j]
  __shared__ __align__(16) u16 Ps[4 * 32 * PS_STR];// per-wave [q][j]

  const int bx = blockIdx.x;
  const int g  = bx >> 5;
  const int bh = bx & 31;
  const int qt = (g & 1) ? (15 - (g >> 1)) : (g >> 1);   // zigzag balance
  const int b = bh >> 4, h = bh & 15;

  const int tid = threadIdx.x, lane = tid & 63, wv = tid >> 6;
  const int quad = lane >> 4, l16 = lane & 15;

  // Q A-fragments: lane holds Q[m = mt*16+l16][d = ks*32 + quad*8 + j]
  frag8 qf[2][4];
  const size_t qbase = ((size_t)(b * SEQ) + qt*128 + wv*32) * HIDDEN + h * HDIM;
#pragma unroll
  for (int mt = 0; mt < 2; mt++)
#pragma unroll
    for (int ks = 0; ks < 4; ks++)
      qf[mt][ks] = *(const frag8*)(Q + qbase + (size_t)(mt*16 + l16) * HIDDEN + ks*32 + quad*8);

  f32x4 Oacc[2][8];
#pragma unroll
  for (int mt = 0; mt < 2; mt++)
#pragma unroll
    for (int dt = 0; dt < 8; dt++) Oacc[mt][dt] = (f32x4)0.0f;
  float m_i[2][4], l_i[2][4];
#pragma unroll
  for (int mt = 0; mt < 2; mt++)
#pragma unroll
    for (int r = 0; r < 4; r++) { m_i[mt][r] = -1e30f; l_i[mt][r] = 0.0f; }

  const int ktmax = 2 * qt + 2;
  const size_t krow0 = (size_t)(b * SEQ) * HIDDEN + h * HDIM;
  const size_t vrow0 = (size_t)(b * HIDDEN + h * HDIM) * SEQ;
  u16* Pw = Ps + wv * (32 * PS_STR);
  const int qmin = qt*128 + wv*32;           // smallest query this wave owns

  for (int kt = 0; kt < ktmax; kt++) {
    // ---- stage K tile [64 keys][128 d]
#pragma unroll
    for (int it = 0; it < 4; it++) {
      const int G = it * 256 + tid;          // 0..1023
      const int key = G >> 4, gd = (G & 15) * 8;
      *(frag8*)&Ks[key * KS_STR + gd] =
        *(const frag8*)(K + krow0 + (size_t)(kt*64 + key) * HIDDEN + gd);
    }
    // ---- stage Vt tile [128 d][64 j] (vector, already transposed in global)
#pragma unroll
    for (int it = 0; it < 4; it++) {
      const int G = it * 256 + tid;
      const int d = G >> 3, j8 = (G & 7) * 8;
      *(frag8*)&Vs[d * VS_STR + j8] =
        *(const frag8*)(Vt + vrow0 + (size_t)d * SEQ + kt*64 + j8);
    }
    __syncthreads();

    const bool active = (qmin + 31 >= kt * 64);   // wave has unmasked work
    if (active) {
      // ---- S = Q*K^T : 32 queries x 64 keys (Q pre-scaled)
      f32x4 st[2][4];
#pragma unroll
      for (int mt = 0; mt < 2; mt++)
#pragma unroll
        for (int jt = 0; jt < 4; jt++) st[mt][jt] = (f32x4)0.0f;

#pragma unroll
      for (int ks = 0; ks < 4; ks++) {
        frag8 kf[4];
#pragma unroll
        for (int jt = 0; jt < 4; jt++)
          kf[jt] = *(const frag8*)&Ks[(jt*16 + l16) * KS_STR + ks*32 + quad*8];
#pragma unroll
        for (int mt = 0; mt < 2; mt++)
#pragma unroll
          for (int jt = 0; jt < 4; jt++)
            st[mt][jt] = __builtin_amdgcn_mfma_f32_16x16x32_bf16(qf[mt][ks], kf[jt], st[mt][jt], 0, 0, 0);
      }

      // ---- causal mask only where the tile crosses the diagonal
      if (kt*64 + 63 > qmin) {
#pragma unroll
        for (int mt = 0; mt < 2; mt++)
#pragma unroll
          for (int jt = 0; jt < 4; jt++) {
            const int j = kt*64 + jt*16 + l16;
#pragma unroll
            for (int r = 0; r < 4; r++) {
              const int m = qmin + mt*16 + quad*4 + r;
              st[mt][jt][r] = (j <= m) ? st[mt][jt][r] : -1e30f;
            }
          }
      }

      // ---- online softmax per query row (mt, r); reduce over l16 lanes
      float alpha[2][4];
#pragma unroll
      for (int mt = 0; mt < 2; mt++)
#pragma unroll
        for (int r = 0; r < 4; r++) {
          float cm = st[mt][0][r];
#pragma unroll
          for (int jt = 1; jt < 4; jt++) cm = fmaxf(cm, st[mt][jt][r]);
          cm = fmaxf(cm, __shfl_xor(cm, 1, 64));
          cm = fmaxf(cm, __shfl_xor(cm, 2, 64));
          cm = fmaxf(cm, __shfl_xor(cm, 4, 64));
          cm = fmaxf(cm, __shfl_xor(cm, 8, 64));
          const float mnew = fmaxf(m_i[mt][r], cm);
          alpha[mt][r] = __expf(m_i[mt][r] - mnew);
          m_i[mt][r] = mnew;
        }

      // ---- p = exp(s - m) (masked -1e30 -> exp gives 0); P -> LDS
      float csum[2][4];
#pragma unroll
      for (int mt = 0; mt < 2; mt++)
#pragma unroll
        for (int r = 0; r < 4; r++) csum[mt][r] = 0.0f;
#pragma unroll
      for (int mt = 0; mt < 2; mt++)
#pragma unroll
        for (int jt = 0; jt < 4; jt++)
#pragma unroll
          for (int r = 0; r < 4; r++) {
            const float p = __expf(st[mt][jt][r] - m_i[mt][r]);
            csum[mt][r] += p;
            Pw[(mt*16 + quad*4 + r) * PS_STR + jt*16 + l16] = f2bf(p);
          }
#pragma unroll
      for (int mt = 0; mt < 2; mt++)
#pragma unroll
        for (int r = 0; r < 4; r++) {
          float cs = csum[mt][r];
          cs += __shfl_xor(cs, 1, 64);
          cs += __shfl_xor(cs, 2, 64);
          cs += __shfl_xor(cs, 4, 64);
          cs += __shfl_xor(cs, 8, 64);
          l_i[mt][r] = l_i[mt][r] * alpha[mt][r] + cs;
#pragma unroll
          for (int dt = 0; dt < 8; dt++) Oacc[mt][dt][r] *= alpha[mt][r];
        }

      // ---- O += P * V  (same-wave LDS RAW on Pw; in-order)
#pragma unroll
      for (int ks2 = 0; ks2 < 2; ks2++) {
        frag8 pf[2];
#pragma unroll
        for (int mt = 0; mt < 2; mt++)
          pf[mt] = *(const frag8*)&Pw[(mt*16 + l16) * PS_STR + ks2*32 + quad*8];
#pragma unroll
        for (int dt = 0; dt < 8; dt++) {
          frag8 vf = *(const frag8*)&Vs[(dt*16 + l16) * VS_STR + ks2*32 + quad*8];
#pragma unroll
          for (int mt = 0; mt < 2; mt++)
            Oacc[mt][dt] = __builtin_amdgcn_mfma_f32_16x16x32_bf16(pf[mt], vf, Oacc[mt][dt], 0, 0, 0);
        }
      }
    }
    __syncthreads();
  }

  // ---- finalize: /l_i, store merged [b*2048+m][h*128+d]
#pragma unroll
  for (int mt = 0; mt < 2; mt++)
#pragma unroll
    for (int r = 0; r < 4; r++) {
      const float inv = 1.0f / l_i[mt][r];
      const int m = qmin + mt*16 + quad*4 + r;
#pragma unroll
      for (int dt = 0; dt < 8; dt++) {
        const int d = dt*16 + l16;
        O[((size_t)(b * SEQ) + m) * HIDDEN + h * HDIM + d] = f2bf(Oacc[mt][dt][r] * inv);
      }
    }
}

// ---------------------------------------------------------------------------
extern "C" void kernel_launch(void* const* d_in, const int* in_sizes, int n_in,
                              void* d_out, int out_size, void* d_ws, size_t ws_size,
                              hipStream_t stream)
{
  const float* X  = (const float*)d_in[0];
  const float* Wq = (const float*)d_in[1];
  const float* bq = (const float*)d_in[2];
  const float* Wk = (const float*)d_in[3];
  const float* bk = (const float*)d_in[4];
  const float* Wv = (const float*)d_in[5];
  const float* bv = (const float*)d_in[6];
  const float* Wo = (const float*)d_in[7];
  const float* bo = (const float*)d_in[8];
  float* out = (float*)d_out;

  // d_out (32 MiB f32) doubles as scratch: Kb [0,16MiB), Xb [16,32MiB).
  // Both dead before the final GEMM overwrites d_out.
  u16* Kb = (u16*)d_out;
  u16* Xb = (u16*)d_out + (8u << 20);
  char* ws = (char*)d_ws;
  u16* Qb  = (u16*)ws;                          // 16 MiB; attn ctx aliases
  u16* Vtb = (u16*)(ws + (16u << 20));          // 16 MiB transposed V

  dim3 blk(256);
  // X -> bf16 (always)
  cvt_kernel<<<4096, blk, 0, stream>>>(X, Xb, 1048576);

  const bool fast = ws_size >= (64u << 20);     // constant per session
  if (fast) {
    u16* Wqb = (u16*)(ws + (32u << 20));
    u16* Wkb = (u16*)(ws + (40u << 20));
    u16* Wvb = (u16*)(ws + (48u << 20));
    u16* Wob = (u16*)(ws + (56u << 20));
    cvt_kernel<<<2048, blk, 0, stream>>>(Wq, Wqb, 524288);
    cvt_kernel<<<2048, blk, 0, stream>>>(Wk, Wkb, 524288);
    cvt_kernel<<<2048, blk, 0, stream>>>(Wv, Wvb, 524288);
    cvt_kernel<<<2048, blk, 0, stream>>>(Wo, Wob, 524288);
    gemm_fused<1,3,1,0><<<dim3(48,32), blk, 0, stream>>>(
        Xb, Wqb, Wkb, Wvb, bq, bk, bv, Qb, Kb, Vtb);
    rope_kernel<<<4096, blk, 0, stream>>>(Qb, Kb);
    attn_kernel<<<512, blk, 0, stream>>>(Qb, Kb, Vtb, Qb);
    gemm_fused<1,1,0,1><<<dim3(16,32), blk, 0, stream>>>(
        Qb, Wob, Wob, Wob, bo, bo, bo, out, out, out);
  } else {
    gemm_fused<0,3,1,0><<<dim3(48,32), blk, 0, stream>>>(
        Xb, Wq, Wk, Wv, bq, bk, bv, Qb, Kb, Vtb);
    rope_kernel<<<4096, blk, 0, stream>>>(Qb, Kb);
    attn_kernel<<<512, blk, 0, stream>>>(Qb, Kb, Vtb, Qb);
    gemm_fused<0,1,0,1><<<dim3(16,32), blk, 0, stream>>>(
        Qb, Wo, Wo, Wo, bo, bo, bo, out, out, out);
  }
}

// Round 6
// 437.126 us; speedup vs baseline: 1.7796x; 1.3380x over previous
//
#include <hip/hip_runtime.h>

using u16 = unsigned short;
using u32 = unsigned int;

typedef __attribute__((ext_vector_type(4))) float f32x4;
typedef __attribute__((ext_vector_type(8))) short frag8;   // 8 x bf16 (4 VGPRs)

#define HIDDEN 2048
#define SEQ    2048
#define NHEADS 16
#define HDIM   128

__device__ __forceinline__ float bf2f(u16 u) {
  union { u32 i; float f; } c; c.i = ((u32)u) << 16; return c.f;
}
__device__ __forceinline__ u16 f2bf(float f) {   // RNE
  union { float f; u32 i; } c; c.f = f;
  u32 u = c.i + 0x7fffu + ((c.i >> 16) & 1u);
  return (u16)(u >> 16);
}

// ---------------------------------------------------------------------------
// Fused f32 -> bf16 convert for X + 4 weight matrices, ONE dispatch.
// X: 4096 blocks (1,048,576 granules of 8); each W: 2048 blocks (524,288).
// Grid = 12288 x 256.
// ---------------------------------------------------------------------------
__global__ void cvt_all(const float* __restrict__ X,
                        const float* __restrict__ W0, const float* __restrict__ W1,
                        const float* __restrict__ W2, const float* __restrict__ W3,
                        u16* __restrict__ dX,
                        u16* __restrict__ dW0, u16* __restrict__ dW1,
                        u16* __restrict__ dW2, u16* __restrict__ dW3)
{
  const int bx = blockIdx.x;
  const float* s; u16* d; int g;
  if (bx < 4096) { s = X; d = dX; g = bx * 256 + threadIdx.x; }
  else {
    const int t = bx - 4096;
    const int w = t >> 11;               // 0..3
    s = (w == 0) ? W0 : (w == 1) ? W1 : (w == 2) ? W2 : W3;
    d = (w == 0) ? dW0 : (w == 1) ? dW1 : (w == 2) ? dW2 : dW3;
    g = (t & 2047) * 256 + threadIdx.x;
  }
  const float* p = s + (size_t)g * 8;
  f32x4 x0 = *(const f32x4*)p, x1 = *(const f32x4*)(p + 4);
  frag8 o;
#pragma unroll
  for (int e = 0; e < 4; e++) { o[e] = (short)f2bf(x0[e]); o[e+4] = (short)f2bf(x1[e]); }
  *(frag8*)(d + (size_t)g * 8) = o;
}

// ---------------------------------------------------------------------------
// Fused NT GEMM:  C[m,n] = sum_k A[m,k] * W[n,k] + bias[n]
// A: bf16 [4096 x 2048] (global_load_lds width=16, m97 structure)
// W: bf16 (W_BF16=1, DMA) or f32 (W_BF16=0, VGPR-convert staging)
// NW: fused weight count (grid.x = NW*16); VT: wix==2 stores transposed
//     Vt[(b*2048 + n)*2048 + s];  C_F32: f32 store (out-proj) else bf16.
// 128x128 tile, BK=32, 16x16x32 bf16 MFMA, fp32 accum.
// ---------------------------------------------------------------------------
template<int W_BF16, int NW, int VT, int C_F32>
__global__ __launch_bounds__(256, 4)
void gemm_fused(const u16* __restrict__ A,
                const void* __restrict__ W0, const void* __restrict__ W1,
                const void* __restrict__ W2,
                const float* __restrict__ bias0, const float* __restrict__ bias1,
                const float* __restrict__ bias2,
                void* __restrict__ C0, void* __restrict__ C1, void* __restrict__ C2)
{
  __shared__ __align__(16) u16 smem[8192];     // As [0,4096), Bs [4096,8192)
  u16* As = smem;
  u16* Bs = smem + 4096;

  const int tid  = threadIdx.x;
  const int lane = tid & 63;
  const int wv   = tid >> 6;
  const int quad = lane >> 4;
  const int l16  = lane & 15;
  const int wm = wv >> 1, wn = wv & 1;
  const int m0 = blockIdx.y * 128;
  const int wix = (NW == 1) ? 0 : (blockIdx.x >> 4);
  const int n0  = ((NW == 1) ? blockIdx.x : (blockIdx.x & 15)) * 128;

  const void* Wp = (wix == 0) ? W0 : (wix == 1) ? W1 : W2;
  const float* bias = (wix == 0) ? bias0 : (wix == 1) ? bias1 : bias2;
  void* Cp = (wix == 0) ? C0 : (wix == 1) ? C1 : C2;

  f32x4 acc[4][4];
#pragma unroll
  for (int i = 0; i < 4; i++)
#pragma unroll
    for (int j = 0; j < 4; j++) acc[i][j] = (f32x4)0.0f;

  // granule g in [0,512): 16B; g -> tile row g>>2, k-col (g&3)*8
  const int g0 = tid, g1 = tid + 256;
  const int r0 = g0 >> 2, c0 = (g0 & 3) * 8;
  const int r1 = g1 >> 2, c1 = (g1 & 3) * 8;

  for (int k0 = 0; k0 < HIDDEN; k0 += 32) {
    __builtin_amdgcn_global_load_lds(
      (const __attribute__((address_space(1))) void*)(A + (size_t)(m0 + r0) * HIDDEN + k0 + c0),
      (__attribute__((address_space(3))) void*)(As + g0 * 8), 16, 0, 0);
    __builtin_amdgcn_global_load_lds(
      (const __attribute__((address_space(1))) void*)(A + (size_t)(m0 + r1) * HIDDEN + k0 + c1),
      (__attribute__((address_space(3))) void*)(As + g1 * 8), 16, 0, 0);
    if (W_BF16) {
      const u16* Wb = (const u16*)Wp;
      __builtin_amdgcn_global_load_lds(
        (const __attribute__((address_space(1))) void*)(Wb + (size_t)(n0 + r0) * HIDDEN + k0 + c0),
        (__attribute__((address_space(3))) void*)(Bs + g0 * 8), 16, 0, 0);
      __builtin_amdgcn_global_load_lds(
        (const __attribute__((address_space(1))) void*)(Wb + (size_t)(n0 + r1) * HIDDEN + k0 + c1),
        (__attribute__((address_space(3))) void*)(Bs + g1 * 8), 16, 0, 0);
    } else {
      const float* Wf = (const float*)Wp;
      const float* p0 = Wf + (size_t)(n0 + r0) * HIDDEN + k0 + c0;
      const float* p1 = Wf + (size_t)(n0 + r1) * HIDDEN + k0 + c1;
      f32x4 x0 = *(const f32x4*)p0, x1 = *(const f32x4*)(p0 + 4);
      f32x4 y0 = *(const f32x4*)p1, y1 = *(const f32x4*)(p1 + 4);
      frag8 b0v, b1v;
#pragma unroll
      for (int e = 0; e < 4; e++) {
        b0v[e]   = (short)f2bf(x0[e]); b0v[e+4] = (short)f2bf(x1[e]);
        b1v[e]   = (short)f2bf(y0[e]); b1v[e+4] = (short)f2bf(y1[e]);
      }
      *(frag8*)&Bs[g0 * 8] = b0v;
      *(frag8*)&Bs[g1 * 8] = b1v;
    }

    __builtin_amdgcn_s_waitcnt(0);   // drain DMA before barrier
    __syncthreads();

    frag8 af[4], bfr[4];
#pragma unroll
    for (int mt = 0; mt < 4; mt++)
      af[mt] = *(const frag8*)&As[(wm*64 + mt*16 + l16) * 32 + quad*8];
#pragma unroll
    for (int nt = 0; nt < 4; nt++)
      bfr[nt] = *(const frag8*)&Bs[(wn*64 + nt*16 + l16) * 32 + quad*8];
#pragma unroll
    for (int mt = 0; mt < 4; mt++)
#pragma unroll
      for (int nt = 0; nt < 4; nt++)
        acc[mt][nt] = __builtin_amdgcn_mfma_f32_16x16x32_bf16(af[mt], bfr[nt], acc[mt][nt], 0, 0, 0);

    __syncthreads();
  }

  // C/D layout (m89/m91): col(n) = lane&15, row(m) = (lane>>4)*4 + reg
  if (VT && wix == 2) {
    u16* Cv = (u16*)Cp;
    u16* T = smem + wv * 1056;    // per-wave 16 x 66 (smem reuse post-barrier)
#pragma unroll
    for (int nt = 0; nt < 4; nt++) {
      const int n  = n0 + wn*64 + nt*16 + l16;
      const float bv = bias[n];
#pragma unroll
      for (int mt = 0; mt < 4; mt++)
#pragma unroll
        for (int r = 0; r < 4; r++)
          T[l16 * 66 + mt*16 + quad*4 + r] = f2bf(acc[mt][nt][r] + bv);
#pragma unroll
      for (int rr = 0; rr < 16; rr++) {
        const int nn = n0 + wn*64 + nt*16 + rr;
        const int mm = m0 + wm*64 + lane;
        const int b = mm >> 11, s = mm & 2047;
        Cv[((size_t)(b * HIDDEN + nn)) * SEQ + s] = T[rr * 66 + lane];
      }
    }
  } else {
#pragma unroll
    for (int nt = 0; nt < 4; nt++) {
      const int n  = n0 + wn*64 + nt*16 + l16;
      const float bv = bias[n];
#pragma unroll
      for (int mt = 0; mt < 4; mt++) {
#pragma unroll
        for (int r = 0; r < 4; r++) {
          const int m = m0 + wm*64 + mt*16 + quad*4 + r;
          if (C_F32) ((float*)Cp)[(size_t)m * HIDDEN + n] = acc[mt][nt][r] + bv;
          else       ((u16*)Cp)[(size_t)m * HIDDEN + n]   = f2bf(acc[mt][nt][r] + bv);
        }
      }
    }
  }
}

// ---------------------------------------------------------------------------
// RoPE in place on bf16 Q,K; 8 d/thread.  Q pre-scaled by 1/sqrt(128).
// ---------------------------------------------------------------------------
__global__ void rope_kernel(u16* __restrict__ Q, u16* __restrict__ K)
{
  const int tid = blockIdx.x * 256 + threadIdx.x;   // 2^20 total
  const int t   = tid >> 19;           // 0:Q 1:K
  const int r   = tid & 524287;
  const int row = r >> 7;              // [0,4096)
  const int grp = r & 127;
  const int h   = grp >> 3, d0 = (grp & 7) * 8;
  u16* X = t ? K : Q;
  const float s = (float)(row & 2047);
  const float qscale = t ? 1.0f : 0.08838834764831845f;
  const size_t base = (size_t)row * HIDDEN + h * HDIM + d0;
  frag8 a = *(const frag8*)(X + base);
  frag8 b = *(const frag8*)(X + base + 64);
  frag8 oa, ob;
#pragma unroll
  for (int e = 0; e < 8; e++) {
    const float inv = __expf(-(float)(d0 + e) * (9.210340371976184f / 64.0f));
    float sn, c;
    __sincosf(s * inv, &sn, &c);
    const float x1 = bf2f((u16)a[e]), x2 = bf2f((u16)b[e]);
    oa[e] = (short)f2bf((x1 * c - x2 * sn) * qscale);
    ob[e] = (short)f2bf((x2 * c + x1 * sn) * qscale);
  }
  *(frag8*)(X + base)      = oa;
  *(frag8*)(X + base + 64) = ob;
}

// ---------------------------------------------------------------------------
// Flash attention (causal).  Q (pre-scaled), K: bf16 [4096][2048];
// Vt: bf16 [(b*2048 + h*128 + d)][s].  O: merged bf16 [4096][2048] (aliases Q).
// Grid 1024 = 32 qt x 32 bh.  Block: 256 thr = 4 waves; Q-tile 64
// (16 q/wave), K-tile 64.  ktmax = qt+1; only kt==qt masks.
// ---------------------------------------------------------------------------
#define KS_STR 132
#define VS_STR 68
#define PS_STR 68
__global__ __launch_bounds__(256, 3)
void attn_kernel(const u16* Q, const u16* __restrict__ K,
                 const u16* __restrict__ Vt, u16* O)
{
  __shared__ __align__(16) u16 Ks[64 * KS_STR];     // [key][d]
  __shared__ __align__(16) u16 Vs[128 * VS_STR];    // [d][j]
  __shared__ __align__(16) u16 Ps[4 * 16 * PS_STR]; // per-wave [q][j]

  const int bx = blockIdx.x;
  const int g  = bx >> 5;                 // [0,32)
  const int bh = bx & 31;
  const int qt = (g & 1) ? (31 - (g >> 1)) : (g >> 1);   // zigzag balance
  const int b = bh >> 4, h = bh & 15;

  const int tid = threadIdx.x, lane = tid & 63, wv = tid >> 6;
  const int quad = lane >> 4, l16 = lane & 15;

  // Q A-fragments: lane holds Q[m = l16][d = ks*32 + quad*8 + j]
  frag8 qf[4];
  const size_t qbase = ((size_t)(b * SEQ) + qt*64 + wv*16) * HIDDEN + h * HDIM;
#pragma unroll
  for (int ks = 0; ks < 4; ks++)
    qf[ks] = *(const frag8*)(Q + qbase + (size_t)l16 * HIDDEN + ks*32 + quad*8);

  f32x4 Oacc[8];
#pragma unroll
  for (int dt = 0; dt < 8; dt++) Oacc[dt] = (f32x4)0.0f;
  float m_i[4], l_i[4];
#pragma unroll
  for (int r = 0; r < 4; r++) { m_i[r] = -1e30f; l_i[r] = 0.0f; }

  const int ktmax = qt + 1;
  const size_t krow0 = (size_t)(b * SEQ) * HIDDEN + h * HDIM;
  const size_t vrow0 = (size_t)(b * HIDDEN + h * HDIM) * SEQ;
  u16* Pw = Ps + wv * (16 * PS_STR);
  const int qmin = qt*64 + wv*16;

  for (int kt = 0; kt < ktmax; kt++) {
    // ---- stage K tile [64 keys][128 d]
#pragma unroll
    for (int it = 0; it < 4; it++) {
      const int G = it * 256 + tid;          // 0..1023
      const int key = G >> 4, gd = (G & 15) * 8;
      *(frag8*)&Ks[key * KS_STR + gd] =
        *(const frag8*)(K + krow0 + (size_t)(kt*64 + key) * HIDDEN + gd);
    }
    // ---- stage Vt tile [128 d][64 j]
#pragma unroll
    for (int it = 0; it < 4; it++) {
      const int G = it * 256 + tid;
      const int d = G >> 3, j8 = (G & 7) * 8;
      *(frag8*)&Vs[d * VS_STR + j8] =
        *(const frag8*)(Vt + vrow0 + (size_t)d * SEQ + kt*64 + j8);
    }
    __syncthreads();

    // ---- S = Q*K^T : 16 queries x 64 keys (Q pre-scaled)
    f32x4 st[4];
#pragma unroll
    for (int jt = 0; jt < 4; jt++) st[jt] = (f32x4)0.0f;

#pragma unroll
    for (int ks = 0; ks < 4; ks++) {
      frag8 kf[4];
#pragma unroll
      for (int jt = 0; jt < 4; jt++)
        kf[jt] = *(const frag8*)&Ks[(jt*16 + l16) * KS_STR + ks*32 + quad*8];
#pragma unroll
      for (int jt = 0; jt < 4; jt++)
        st[jt] = __builtin_amdgcn_mfma_f32_16x16x32_bf16(qf[ks], kf[jt], st[jt], 0, 0, 0);
    }

    // ---- causal mask on the diagonal tile only
    if (kt == qt) {
#pragma unroll
      for (int jt = 0; jt < 4; jt++) {
        const int jl = jt*16 + l16;          // key - kt*64
#pragma unroll
        for (int r = 0; r < 4; r++) {
          const int ml = wv*16 + quad*4 + r; // query - qt*64
          st[jt][r] = (jl <= ml) ? st[jt][r] : -1e30f;
        }
      }
    }

    // ---- online softmax per query row (r); reduce over l16 lanes
    float alpha[4];
#pragma unroll
    for (int r = 0; r < 4; r++) {
      float cm = st[0][r];
#pragma unroll
      for (int jt = 1; jt < 4; jt++) cm = fmaxf(cm, st[jt][r]);
      cm = fmaxf(cm, __shfl_xor(cm, 1, 64));
      cm = fmaxf(cm, __shfl_xor(cm, 2, 64));
      cm = fmaxf(cm, __shfl_xor(cm, 4, 64));
      cm = fmaxf(cm, __shfl_xor(cm, 8, 64));
      const float mnew = fmaxf(m_i[r], cm);
      alpha[r] = __expf(m_i[r] - mnew);
      m_i[r] = mnew;
    }

    // ---- p = exp(s - m); P -> LDS
    float csum[4];
#pragma unroll
    for (int r = 0; r < 4; r++) csum[r] = 0.0f;
#pragma unroll
    for (int jt = 0; jt < 4; jt++)
#pragma unroll
      for (int r = 0; r < 4; r++) {
        const float p = __expf(st[jt][r] - m_i[r]);
        csum[r] += p;
        Pw[(quad*4 + r) * PS_STR + jt*16 + l16] = f2bf(p);
      }
#pragma unroll
    for (int r = 0; r < 4; r++) {
      float cs = csum[r];
      cs += __shfl_xor(cs, 1, 64);
      cs += __shfl_xor(cs, 2, 64);
      cs += __shfl_xor(cs, 4, 64);
      cs += __shfl_xor(cs, 8, 64);
      l_i[r] = l_i[r] * alpha[r] + cs;
#pragma unroll
      for (int dt = 0; dt < 8; dt++) Oacc[dt][r] *= alpha[r];
    }

    // ---- O += P * V  (same-wave LDS RAW on Pw)
#pragma unroll
    for (int ks2 = 0; ks2 < 2; ks2++) {
      frag8 pf = *(const frag8*)&Pw[l16 * PS_STR + ks2*32 + quad*8];
#pragma unroll
      for (int dt = 0; dt < 8; dt++) {
        frag8 vf = *(const frag8*)&Vs[(dt*16 + l16) * VS_STR + ks2*32 + quad*8];
        Oacc[dt] = __builtin_amdgcn_mfma_f32_16x16x32_bf16(pf, vf, Oacc[dt], 0, 0, 0);
      }
    }
    __syncthreads();
  }

  // ---- finalize: /l_i, store merged [b*2048+m][h*128+d]
#pragma unroll
  for (int r = 0; r < 4; r++) {
    const float inv = 1.0f / l_i[r];
    const int m = qmin + quad*4 + r;
#pragma unroll
    for (int dt = 0; dt < 8; dt++) {
      const int d = dt*16 + l16;
      O[((size_t)(b * SEQ) + m) * HIDDEN + h * HDIM + d] = f2bf(Oacc[dt][r] * inv);
    }
  }
}

// ---------------------------------------------------------------------------
extern "C" void kernel_launch(void* const* d_in, const int* in_sizes, int n_in,
                              void* d_out, int out_size, void* d_ws, size_t ws_size,
                              hipStream_t stream)
{
  const float* X  = (const float*)d_in[0];
  const float* Wq = (const float*)d_in[1];
  const float* bq = (const float*)d_in[2];
  const float* Wk = (const float*)d_in[3];
  const float* bk = (const float*)d_in[4];
  const float* Wv = (const float*)d_in[5];
  const float* bv = (const float*)d_in[6];
  const float* Wo = (const float*)d_in[7];
  const float* bo = (const float*)d_in[8];
  float* out = (float*)d_out;

  // d_out (32 MiB f32) doubles as scratch: Kb [0,16MiB), Xb [16,32MiB).
  u16* Kb = (u16*)d_out;
  u16* Xb = (u16*)d_out + (8u << 20);
  char* ws = (char*)d_ws;
  u16* Qb  = (u16*)ws;                          // 16 MiB; attn ctx aliases
  u16* Vtb = (u16*)(ws + (16u << 20));          // 16 MiB transposed V

  dim3 blk(256);
  const bool fast = ws_size >= (64u << 20);     // constant per session
  if (fast) {
    u16* Wqb = (u16*)(ws + (32u << 20));
    u16* Wkb = (u16*)(ws + (40u << 20));
    u16* Wvb = (u16*)(ws + (48u << 20));
    u16* Wob = (u16*)(ws + (56u << 20));
    cvt_all<<<12288, blk, 0, stream>>>(X, Wq, Wk, Wv, Wo, Xb, Wqb, Wkb, Wvb, Wob);
    gemm_fused<1,3,1,0><<<dim3(48,32), blk, 0, stream>>>(
        Xb, Wqb, Wkb, Wvb, bq, bk, bv, Qb, Kb, Vtb);
    rope_kernel<<<4096, blk, 0, stream>>>(Qb, Kb);
    attn_kernel<<<1024, blk, 0, stream>>>(Qb, Kb, Vtb, Qb);
    gemm_fused<1,1,0,1><<<dim3(16,32), blk, 0, stream>>>(
        Qb, Wob, Wob, Wob, bo, bo, bo, out, out, out);
  } else {
    cvt_all<<<4096, blk, 0, stream>>>(X, Wq, Wk, Wv, Wo, Xb, Xb, Xb, Xb, Xb); // X only (W blocks absent)
    gemm_fused<0,3,1,0><<<dim3(48,32), blk, 0, stream>>>(
        Xb, Wq, Wk, Wv, bq, bk, bv, Qb, Kb, Vtb);
    rope_kernel<<<4096, blk, 0, stream>>>(Qb, Kb);
    attn_kernel<<<1024, blk, 0, stream>>>(Qb, Kb, Vtb, Qb);
    gemm_fused<0,1,0,1><<<dim3(16,32), blk, 0, stream>>>(
        Qb, Wo, Wo, Wo, bo, bo, bo, out, out, out);
  }
}